// Round 13
// baseline (570.408 us; speedup 1.0000x reference)
//
#include <hip/hip_runtime.h>

#define N_USER 100000
#define N_ITEM 200000
#define N_TOT  (N_USER + N_ITEM)
#define D      64
#define RPB    64                        // rows per bucket
#define NB     ((N_TOT + RPB - 1) / RPB) // 4688 buckets
#define NSB    ((NB + 63) / 64)          // 74 super-buckets (4096 rows each)
#define SLICES 8                         // binB blocks per super
#define NBLK_A 512                       // binA blocks
#define CAP    2560                      // sortgather LDS edge capacity per chunk
#define SCAN_CHUNK 2048                  // tier-2 scan

__device__ __forceinline__ unsigned short f2bf(float f) {
    unsigned b = __float_as_uint(f);
    unsigned r = (b + 0x7FFFu + ((b >> 16) & 1u)) >> 16;   // RNE
    return (unsigned short)r;
}
__device__ __forceinline__ float bf2f(unsigned short u) {
    return __uint_as_float(((unsigned)u) << 16);
}

// ================= emb -> bf16 =================
__global__ __launch_bounds__(256) void conv_kernel(const float* __restrict__ users,
                                                   const float* __restrict__ items,
                                                   ushort* __restrict__ emb16) {
    size_t i = (size_t)blockIdx.x * blockDim.x + threadIdx.x;
    const size_t total = (size_t)N_TOT * D / 4;
    if (i >= total) return;
    size_t e0 = i * 4;
    const size_t usz = (size_t)N_USER * D;
    const float* src = (e0 < usz) ? users + e0 : items + (e0 - usz);
    float4 v = *reinterpret_cast<const float4*>(src);
    ushort4 o;
    o.x = f2bf(v.x); o.y = f2bf(v.y); o.z = f2bf(v.z); o.w = f2bf(v.w);
    *reinterpret_cast<ushort4*>(emb16 + e0) = o;
}

// ===== pass A: bin into 74 fixed-capacity super regions (no prior count needed) =====
__global__ __launch_bounds__(512) void binA_kernel(const int* __restrict__ rows,
                                                   const int* __restrict__ cols,
                                                   const float* __restrict__ vals,
                                                   int* __restrict__ gcurA,
                                                   unsigned* __restrict__ eg1m,
                                                   ushort* __restrict__ eg1v,
                                                   int nnz, int chunk, int cap_s) {
    __shared__ int h[NSB];
    const int tid = threadIdx.x;
    if (tid < NSB) h[tid] = 0;
    __syncthreads();
    int lo = blockIdx.x * chunk;
    int hi = min(lo + chunk, nnz);
    for (int i = lo + tid; i < hi; i += 512)
        atomicAdd(&h[rows[i] >> 12], 1);
    __syncthreads();
    if (tid < NSB && h[tid])
        h[tid] = atomicAdd(&gcurA[tid], h[tid]);    // base offset within super region
    __syncthreads();
    for (int i = lo + tid; i < hi; i += 512) {
        int r = rows[i];                             // L2-hot
        int s = r >> 12;
        int slot = atomicAdd(&h[s], 1);
        size_t p = (size_t)s * cap_s + slot;
        eg1m[p] = ((unsigned)(r & 4095) << 19) | (unsigned)cols[i];
        eg1v[p] = f2bf(vals[i]);
    }
}

// ===== pass B1: per-(super,slice) 64-bin histogram =====
__global__ __launch_bounds__(512) void binBh_kernel(const int* __restrict__ lenA,
                                                    const unsigned* __restrict__ eg1m,
                                                    int* __restrict__ H, int cap_s) {
    __shared__ int h[64];
    const int sb = blockIdx.x / SLICES;
    const int sl = blockIdx.x % SLICES;
    const int len = lenA[sb];
    const int chunk = (len + SLICES - 1) / SLICES;
    const int lo = sl * chunk;
    const int hi = min(lo + chunk, len);
    const size_t base = (size_t)sb * cap_s;
    if (threadIdx.x < 64) h[threadIdx.x] = 0;
    __syncthreads();
    for (int i = lo + threadIdx.x; i < hi; i += 512)
        atomicAdd(&h[(eg1m[base + i] >> 25) & 63], 1);
    __syncthreads();
    if (threadIdx.x < 64)
        H[((size_t)sb * SLICES + sl) * 64 + threadIdx.x] = h[threadIdx.x];
}

// ===== scan: super lens -> superstart; H -> per-slice write bases + bstart =====
__global__ __launch_bounds__(128) void scan_all(const int* __restrict__ lenA,
                                                int* __restrict__ H,
                                                int* __restrict__ bstart, int nnz) {
    __shared__ int ss[NSB + 1];
    const int t = threadIdx.x;
    if (t == 0) {
        int acc = 0;
        for (int s = 0; s < NSB; ++s) { ss[s] = acc; acc += lenA[s]; }
        ss[NSB] = acc;
    }
    __syncthreads();
    for (int sb = t; sb < NSB; sb += 128) {
        int base = ss[sb];
        int nbk = min(64, NB - sb * 64);
        for (int b = 0; b < nbk; ++b) {
            bstart[sb * 64 + b] = base;
            int cur = base;
            for (int sl = 0; sl < SLICES; ++sl) {
                size_t idx = ((size_t)sb * SLICES + sl) * 64 + b;
                int c = H[idx];
                H[idx] = cur;
                cur += c;
            }
            base = cur;
        }
    }
    if (t == 0) bstart[NB] = nnz;
}

// ===== pass B2: scatter each slice into bucket-contiguous eg2 =====
__global__ __launch_bounds__(512) void binBs_kernel(const int* __restrict__ lenA,
                                                    const unsigned* __restrict__ eg1m,
                                                    const ushort* __restrict__ eg1v,
                                                    const int* __restrict__ H,
                                                    unsigned* __restrict__ eg2m,
                                                    ushort* __restrict__ eg2v, int cap_s) {
    __shared__ int cur[64];
    const int sb = blockIdx.x / SLICES;
    const int sl = blockIdx.x % SLICES;
    const int len = lenA[sb];
    const int chunk = (len + SLICES - 1) / SLICES;
    const int lo = sl * chunk;
    const int hi = min(lo + chunk, len);
    const size_t base = (size_t)sb * cap_s;
    if (threadIdx.x < 64)
        cur[threadIdx.x] = H[((size_t)sb * SLICES + sl) * 64 + threadIdx.x];
    __syncthreads();
    for (int i = lo + threadIdx.x; i < hi; i += 512) {
        unsigned m = eg1m[base + i];                 // L2-hot after binBh
        ushort  v = eg1v[base + i];
        int slot = atomicAdd(&cur[(m >> 25) & 63], 1);
        eg2m[slot] = m;
        eg2v[slot] = v;
    }
}

// ======= fused: in-LDS row sort + base + neighbor + gather, one block per bucket =======
__global__ __launch_bounds__(256) void sortgather_kernel(
    const ushort* __restrict__ emb16,
    const int*   __restrict__ unb,   const float* __restrict__ uw,
    const int*   __restrict__ inb,   const float* __restrict__ iw,
    const int*   __restrict__ bstart,
    const unsigned* __restrict__ eg2m, const ushort* __restrict__ eg2v,
    float* __restrict__ out)
{
    __shared__ unsigned lds_m[CAP];       // 10 KB
    __shared__ ushort   lds_v[CAP];       // 5 KB
    __shared__ int h[RPB], st[RPB], cur[RPB];

    const int tid  = threadIdx.x;
    const int g    = tid >> 4;            // 16 groups
    const int sub  = tid & 15;
    const int d0   = sub * 4;
    const int k    = blockIdx.x;
    const int row0 = k * RPB;

    float4 acc[4];
    #pragma unroll
    for (int rr = 0; rr < 4; ++rr) {
        const int row = row0 + rr * 16 + g;
        if (row >= N_TOT) { acc[rr] = make_float4(0.f, 0.f, 0.f, 0.f); continue; }
        ushort4 ub = *reinterpret_cast<const ushort4*>(emb16 + (size_t)row * D + d0);
        float4 a = make_float4(bf2f(ub.x), bf2f(ub.y), bf2f(ub.z), bf2f(ub.w));
        if (row < N_USER) {
            const int*   nb = unb + (size_t)row * 10;
            const float* w  = uw  + (size_t)row * 10;
            #pragma unroll
            for (int q = 0; q < 10; ++q) {
                ushort4 u = *reinterpret_cast<const ushort4*>(emb16 + (size_t)nb[q] * D + d0);
                float wq = w[q];
                a.x += wq * bf2f(u.x); a.y += wq * bf2f(u.y);
                a.z += wq * bf2f(u.z); a.w += wq * bf2f(u.w);
            }
        } else {
            const int r = row - N_USER;
            const int*   nb = inb + (size_t)r * 10;
            const float* w  = iw  + (size_t)r * 10;
            #pragma unroll
            for (int q = 0; q < 10; ++q) {
                ushort4 u = *reinterpret_cast<const ushort4*>(emb16 + ((size_t)nb[q] + N_USER) * D + d0);
                float wq = w[q];
                a.x += wq * bf2f(u.x); a.y += wq * bf2f(u.y);
                a.z += wq * bf2f(u.z); a.w += wq * bf2f(u.w);
            }
        }
        acc[rr] = a;
    }

    const int s = bstart[k];
    const int e = bstart[k + 1];

    for (int cs = s; cs < e; cs += CAP) {
        const int n = min(e - cs, CAP);

        if (tid < RPB) h[tid] = 0;
        __syncthreads();
        for (int i = tid; i < n; i += 256)
            atomicAdd(&h[(eg2m[cs + i] >> 19) & 63], 1);
        __syncthreads();
        if (tid < RPB) {                  // wave 0: 64-wide shfl scan
            int orig = h[tid];
            int v = orig;
            #pragma unroll
            for (int off = 1; off < RPB; off <<= 1) {
                int u = __shfl_up(v, off);
                if (tid >= off) v += u;
            }
            st[tid]  = v - orig;
            cur[tid] = v - orig;
        }
        __syncthreads();
        for (int i = tid; i < n; i += 256) {
            unsigned m = eg2m[cs + i];    // L2 hit
            ushort  v = eg2v[cs + i];
            int slot = atomicAdd(&cur[(m >> 19) & 63], 1);
            lds_m[slot] = m;
            lds_v[slot] = v;
        }
        __syncthreads();

        #pragma unroll
        for (int rr = 0; rr < 4; ++rr) {
            const int r  = rr * 16 + g;
            const int b0 = st[r];
            const int cr = h[r];
            int j = 0;
            for (; j + 3 < cr; j += 4) {
                unsigned m0 = lds_m[b0 + j],     m1 = lds_m[b0 + j + 1];
                unsigned m2 = lds_m[b0 + j + 2], m3 = lds_m[b0 + j + 3];
                float a0 = bf2f(lds_v[b0 + j]),     a1 = bf2f(lds_v[b0 + j + 1]);
                float a2 = bf2f(lds_v[b0 + j + 2]), a3 = bf2f(lds_v[b0 + j + 3]);
                ushort4 u0 = *reinterpret_cast<const ushort4*>(emb16 + (size_t)(m0 & 0x7FFFFu) * D + d0);
                ushort4 u1 = *reinterpret_cast<const ushort4*>(emb16 + (size_t)(m1 & 0x7FFFFu) * D + d0);
                ushort4 u2 = *reinterpret_cast<const ushort4*>(emb16 + (size_t)(m2 & 0x7FFFFu) * D + d0);
                ushort4 u3 = *reinterpret_cast<const ushort4*>(emb16 + (size_t)(m3 & 0x7FFFFu) * D + d0);
                acc[rr].x += a0 * bf2f(u0.x); acc[rr].y += a0 * bf2f(u0.y);
                acc[rr].z += a0 * bf2f(u0.z); acc[rr].w += a0 * bf2f(u0.w);
                acc[rr].x += a1 * bf2f(u1.x); acc[rr].y += a1 * bf2f(u1.y);
                acc[rr].z += a1 * bf2f(u1.z); acc[rr].w += a1 * bf2f(u1.w);
                acc[rr].x += a2 * bf2f(u2.x); acc[rr].y += a2 * bf2f(u2.y);
                acc[rr].z += a2 * bf2f(u2.z); acc[rr].w += a2 * bf2f(u2.w);
                acc[rr].x += a3 * bf2f(u3.x); acc[rr].y += a3 * bf2f(u3.y);
                acc[rr].z += a3 * bf2f(u3.z); acc[rr].w += a3 * bf2f(u3.w);
            }
            for (; j < cr; ++j) {
                unsigned m = lds_m[b0 + j];
                float a = bf2f(lds_v[b0 + j]);
                ushort4 u = *reinterpret_cast<const ushort4*>(emb16 + (size_t)(m & 0x7FFFFu) * D + d0);
                acc[rr].x += a * bf2f(u.x); acc[rr].y += a * bf2f(u.y);
                acc[rr].z += a * bf2f(u.z); acc[rr].w += a * bf2f(u.w);
            }
        }
        __syncthreads();
    }

    #pragma unroll
    for (int rr = 0; rr < 4; ++rr) {
        const int row = row0 + rr * 16 + g;
        if (row < N_TOT)
            *reinterpret_cast<float4*>(&out[(size_t)row * D + d0]) = acc[rr];
    }
}

// ================= tier-2: CSR build via global atomics + fp32 gather =================

__global__ void count_kernel(const int* __restrict__ rows, int* __restrict__ cnt, int nnz) {
    int i = blockIdx.x * blockDim.x + threadIdx.x;
    int stride = gridDim.x * blockDim.x;
    for (; i < nnz; i += stride) atomicAdd(&cnt[rows[i]], 1);
}

__global__ void scan_block_sums(const int* __restrict__ cnt, int* __restrict__ bsum, int n) {
    __shared__ int sdata[256];
    int base = blockIdx.x * SCAN_CHUNK;
    int s = 0;
    for (int t = threadIdx.x; t < SCAN_CHUNK; t += 256) {
        int idx = base + t;
        s += (idx < n) ? cnt[idx] : 0;
    }
    sdata[threadIdx.x] = s;
    __syncthreads();
    for (int off = 128; off > 0; off >>= 1) {
        if (threadIdx.x < off) sdata[threadIdx.x] += sdata[threadIdx.x + off];
        __syncthreads();
    }
    if (threadIdx.x == 0) bsum[blockIdx.x] = sdata[0];
}

__global__ void scan_bsum_kernel(int* __restrict__ bsum, int nb) {
    if (threadIdx.x == 0 && blockIdx.x == 0) {
        int acc = 0;
        for (int i = 0; i < nb; ++i) { int v = bsum[i]; bsum[i] = acc; acc += v; }
    }
}

__global__ void scan_final(const int* __restrict__ cnt, const int* __restrict__ bsum,
                           int* __restrict__ row_start, int n, int nnz) {
    __shared__ int sums[256];
    int b = blockIdx.x, t = threadIdx.x;
    int base = b * SCAN_CHUNK;
    int loc[8];
    int s = 0;
    #pragma unroll
    for (int k = 0; k < 8; ++k) {
        int idx = base + t * 8 + k;
        int v = (idx < n) ? cnt[idx] : 0;
        loc[k] = s; s += v;
    }
    sums[t] = s;
    __syncthreads();
    for (int off = 1; off < 256; off <<= 1) {
        int v = (t >= off) ? sums[t - off] : 0;
        __syncthreads();
        sums[t] += v;
        __syncthreads();
    }
    int off0 = bsum[b] + (sums[t] - s);
    #pragma unroll
    for (int k = 0; k < 8; ++k) {
        int idx = base + t * 8 + k;
        if (idx < n) row_start[idx] = off0 + loc[k];
    }
    if (b == gridDim.x - 1 && t == 255) row_start[n] = nnz;
}

__global__ void fill_kernel(const int* __restrict__ rows, const int* __restrict__ cols,
                            const float* __restrict__ vals, const int* __restrict__ row_start,
                            int* __restrict__ pos, uint2* __restrict__ eg, int nnz) {
    int i = blockIdx.x * blockDim.x + threadIdx.x;
    int stride = gridDim.x * blockDim.x;
    for (; i < nnz; i += stride) {
        int r = rows[i];
        int p = atomicAdd(&pos[r], 1);
        uint2 e;
        e.x = (unsigned)cols[i];
        e.y = __float_as_uint(vals[i]);
        eg[row_start[r] + p] = e;
    }
}

__global__ __launch_bounds__(256) void gather16_kernel(
    const float* __restrict__ users, const float* __restrict__ items,
    const int*   __restrict__ unb,   const float* __restrict__ uw,
    const int*   __restrict__ inb,   const float* __restrict__ iw,
    const int*   __restrict__ row_start, const uint2* __restrict__ eg,
    float* __restrict__ out)
{
    const int tid = threadIdx.x;
    const int grp = tid >> 4;
    const int sub = tid & 15;
    const int row = blockIdx.x * 16 + grp;
    if (row >= N_TOT) return;
    const int d0 = sub * 4;

    float4 acc;
    if (row < N_USER) {
        acc = *reinterpret_cast<const float4*>(&users[(size_t)row * D + d0]);
        const int*   nb = unb + (size_t)row * 10;
        const float* w  = uw  + (size_t)row * 10;
        #pragma unroll
        for (int q = 0; q < 10; ++q) {
            float4 v = *reinterpret_cast<const float4*>(&users[(size_t)nb[q] * D + d0]);
            float wq = w[q];
            acc.x += wq * v.x; acc.y += wq * v.y; acc.z += wq * v.z; acc.w += wq * v.w;
        }
    } else {
        int r = row - N_USER;
        acc = *reinterpret_cast<const float4*>(&items[(size_t)r * D + d0]);
        const int*   nb = inb + (size_t)r * 10;
        const float* w  = iw  + (size_t)r * 10;
        #pragma unroll
        for (int q = 0; q < 10; ++q) {
            float4 v = *reinterpret_cast<const float4*>(&items[(size_t)nb[q] * D + d0]);
            float wq = w[q];
            acc.x += wq * v.x; acc.y += wq * v.y; acc.z += wq * v.z; acc.w += wq * v.w;
        }
    }

    const int s = row_start[row];
    const int e = row_start[row + 1];
    for (int i = s; i < e; ++i) {
        uint2 p = eg[i];
        int c = (int)(p.x & 0x7FFFFu);
        const float* src = (c < N_USER) ? users + (size_t)c * D : items + (size_t)(c - N_USER) * D;
        float4 v = *reinterpret_cast<const float4*>(src + d0);
        float a = __uint_as_float(p.y);
        acc.x += a * v.x; acc.y += a * v.y; acc.z += a * v.z; acc.w += a * v.w;
    }

    *reinterpret_cast<float4*>(&out[(size_t)row * D + d0]) = acc;
}

// ================= tier-3 fallback: scatter =================
__global__ __launch_bounds__(256) void base_neighbor_kernel(
    const float* __restrict__ users, const float* __restrict__ items,
    const int*   __restrict__ unb,   const float* __restrict__ uw,
    const int*   __restrict__ inb,   const float* __restrict__ iw,
    float* __restrict__ out)
{
    int gtid = blockIdx.x * blockDim.x + threadIdx.x;
    int row  = gtid >> 6;
    int lane = gtid & 63;
    if (row >= N_TOT) return;
    float acc;
    if (row < N_USER) {
        acc = users[(size_t)row * D + lane];
        const int*   nb = unb + (size_t)row * 10;
        const float* w  = uw  + (size_t)row * 10;
        #pragma unroll
        for (int q = 0; q < 10; ++q) acc += w[q] * users[(size_t)nb[q] * D + lane];
    } else {
        int r = row - N_USER;
        acc = items[(size_t)r * D + lane];
        const int*   nb = inb + (size_t)r * 10;
        const float* w  = iw  + (size_t)r * 10;
        #pragma unroll
        for (int q = 0; q < 10; ++q) acc += w[q] * items[(size_t)nb[q] * D + lane];
    }
    out[(size_t)row * D + lane] = acc;
}

__global__ __launch_bounds__(256) void edge_scatter_kernel(
    const float* __restrict__ users, const float* __restrict__ items,
    const int*   __restrict__ rows,  const int* __restrict__ cols,
    const float* __restrict__ vals,
    float* __restrict__ out, int nnz)
{
    int gtid = blockIdx.x * blockDim.x + threadIdx.x;
    int e    = gtid >> 6;
    int lane = gtid & 63;
    if (e >= nnz) return;
    int   r = rows[e];
    int   c = cols[e];
    float v = vals[e];
    const float* src = (c < N_USER) ? (users + (size_t)c * D)
                                    : (items + (size_t)(c - N_USER) * D);
    atomicAdd(&out[(size_t)r * D + lane], v * src[lane]);
}

extern "C" void kernel_launch(void* const* d_in, const int* in_sizes, int n_in,
                              void* d_out, int out_size, void* d_ws, size_t ws_size,
                              hipStream_t stream) {
    const float* users = (const float*)d_in[0];
    const float* items = (const float*)d_in[1];
    const int*   unb   = (const int*)  d_in[2];
    const float* uw    = (const float*)d_in[3];
    const int*   inb   = (const int*)  d_in[4];
    const float* iw    = (const float*)d_in[5];
    const int*   grow  = (const int*)  d_in[6];
    const int*   gcol  = (const int*)  d_in[7];
    const float* gval  = (const float*)d_in[8];
    float* out = (float*)d_out;

    const int nnz = in_sizes[6];
    const int cap_s = nnz / NSB + 16384;   // ~45 sigma slack over Poisson spread

    const size_t A = 255;
    const size_t sz_eg1m   = (((size_t)NSB * cap_s * 4) + A) & ~A;
    const size_t sz_eg1v   = (((size_t)NSB * cap_s * 2) + A) & ~A;
    const size_t sz_eg2m   = (((size_t)nnz * 4) + A) & ~A;
    const size_t sz_eg2v   = (((size_t)nnz * 2) + A) & ~A;
    const size_t sz_H      = (((size_t)NSB * SLICES * 64 * 4) + A) & ~A;
    const size_t sz_bstart = (((size_t)(NB + 1) * 4) + A) & ~A;
    const size_t sz_gcurA  = (((size_t)NSB * 4) + A) & ~A;
    const size_t sz_emb16  = (((size_t)N_TOT * D * 2) + A) & ~A;
    const size_t need0 = sz_eg1m + sz_eg1v + sz_eg2m + sz_eg2v + sz_H
                       + sz_bstart + sz_gcurA + sz_emb16;

    const size_t sz_eg       = (((size_t)nnz * 8) + A) & ~A;
    const size_t sz_rowstart = (((size_t)(N_TOT + 1) * 4) + A) & ~A;
    const size_t sz_cnt  = (((size_t)N_TOT * 4) + A) & ~A;
    const int    nb2     = (N_TOT + SCAN_CHUNK - 1) / SCAN_CHUNK;
    const size_t sz_bsum = (((size_t)nb2 * 4) + A) & ~A;
    const size_t need2 = sz_eg + sz_rowstart + sz_cnt + sz_bsum;

    if (ws_size >= need0) {
        char* wsp = (char*)d_ws;
        unsigned* eg1m   = (unsigned*)wsp;  wsp += sz_eg1m;
        ushort*   eg1v   = (ushort*)wsp;    wsp += sz_eg1v;
        unsigned* eg2m   = (unsigned*)wsp;  wsp += sz_eg2m;
        ushort*   eg2v   = (ushort*)wsp;    wsp += sz_eg2v;
        int*      H      = (int*)wsp;       wsp += sz_H;
        int*      bstart = (int*)wsp;       wsp += sz_bstart;
        int*      gcurA  = (int*)wsp;       wsp += sz_gcurA;
        ushort*   emb16  = (ushort*)wsp;

        const int chunkA = (nnz + NBLK_A - 1) / NBLK_A;
        const int conv_grid = (int)(((size_t)N_TOT * D / 4 + 255) / 256);

        conv_kernel<<<conv_grid, 256, 0, stream>>>(users, items, emb16);
        hipMemsetAsync(gcurA, 0, (size_t)NSB * 4, stream);
        binA_kernel<<<NBLK_A, 512, 0, stream>>>(grow, gcol, gval, gcurA,
                                                eg1m, eg1v, nnz, chunkA, cap_s);
        binBh_kernel<<<NSB * SLICES, 512, 0, stream>>>(gcurA, eg1m, H, cap_s);
        scan_all<<<1, 128, 0, stream>>>(gcurA, H, bstart, nnz);
        binBs_kernel<<<NSB * SLICES, 512, 0, stream>>>(gcurA, eg1m, eg1v, H,
                                                       eg2m, eg2v, cap_s);
        sortgather_kernel<<<NB, 256, 0, stream>>>(emb16, unb, uw, inb, iw,
                                                  bstart, eg2m, eg2v, out);
    } else if (ws_size >= need2) {
        char* wsp = (char*)d_ws;
        uint2* eg        = (uint2*)wsp;  wsp += sz_eg;
        int*   row_start = (int*)wsp;    wsp += sz_rowstart;
        int*   cnt       = (int*)wsp;    wsp += sz_cnt;
        int*   bsum      = (int*)wsp;

        hipMemsetAsync(cnt, 0, (size_t)N_TOT * 4, stream);
        count_kernel<<<2048, 256, 0, stream>>>(grow, cnt, nnz);
        scan_block_sums<<<nb2, 256, 0, stream>>>(cnt, bsum, N_TOT);
        scan_bsum_kernel<<<1, 64, 0, stream>>>(bsum, nb2);
        scan_final<<<nb2, 256, 0, stream>>>(cnt, bsum, row_start, N_TOT, nnz);
        hipMemsetAsync(cnt, 0, (size_t)N_TOT * 4, stream);
        fill_kernel<<<2048, 256, 0, stream>>>(grow, gcol, gval, row_start, cnt, eg, nnz);
        const int g16_grid = (N_TOT + 15) / 16;
        gather16_kernel<<<g16_grid, 256, 0, stream>>>(users, items, unb, uw, inb, iw,
                                                      row_start, eg, out);
    } else {
        int grid = (int)(((long long)N_TOT * 64 + 255) / 256);
        base_neighbor_kernel<<<grid, 256, 0, stream>>>(users, items, unb, uw, inb, iw, out);
        long long ethreads = (long long)nnz * 64;
        long long egrid = (ethreads + 255) / 256;
        edge_scatter_kernel<<<(int)egrid, 256, 0, stream>>>(users, items, grow, gcol, gval, out, nnz);
    }
}

// Round 14
// 508.063 us; speedup vs baseline: 1.1227x; 1.1227x over previous
//
#include <hip/hip_runtime.h>

#define N_USER 100000
#define N_ITEM 200000
#define N_TOT  (N_USER + N_ITEM)
#define D      64
#define RPB    64                        // rows per bucket
#define NB     ((N_TOT + RPB - 1) / RPB) // 4688 buckets
#define NSB    ((NB + 63) / 64)          // 74 super-buckets (4096 rows each)
#define SLICES 8                         // binB blocks per super
#define NBLK_A 512                       // binA blocks
#define CAP    2304                      // sortgather LDS edge capacity per chunk
#define SCAN_CHUNK 2048                  // tier-2 scan

__device__ __forceinline__ unsigned short f2bf(float f) {
    unsigned b = __float_as_uint(f);
    unsigned r = (b + 0x7FFFu + ((b >> 16) & 1u)) >> 16;   // RNE
    return (unsigned short)r;
}
__device__ __forceinline__ float bf2f(unsigned short u) {
    return __uint_as_float(((unsigned)u) << 16);
}

// ================= emb -> bf16 =================
__global__ __launch_bounds__(256) void conv_kernel(const float* __restrict__ users,
                                                   const float* __restrict__ items,
                                                   ushort* __restrict__ emb16) {
    size_t i = (size_t)blockIdx.x * blockDim.x + threadIdx.x;
    const size_t total = (size_t)N_TOT * D / 4;
    if (i >= total) return;
    size_t e0 = i * 4;
    const size_t usz = (size_t)N_USER * D;
    const float* src = (e0 < usz) ? users + e0 : items + (e0 - usz);
    float4 v = *reinterpret_cast<const float4*>(src);
    ushort4 o;
    o.x = f2bf(v.x); o.y = f2bf(v.y); o.z = f2bf(v.z); o.w = f2bf(v.w);
    *reinterpret_cast<ushort4*>(emb16 + e0) = o;
}

// ===== pass A: bin into 74 fixed-capacity super regions (no prior count needed) =====
__global__ __launch_bounds__(512) void binA_kernel(const int* __restrict__ rows,
                                                   const int* __restrict__ cols,
                                                   const float* __restrict__ vals,
                                                   int* __restrict__ gcurA,
                                                   uint2* __restrict__ eg1,
                                                   int nnz, int chunk, int cap_s) {
    __shared__ int h[NSB];
    const int tid = threadIdx.x;
    if (tid < NSB) h[tid] = 0;
    __syncthreads();
    int lo = blockIdx.x * chunk;
    int hi = min(lo + chunk, nnz);
    for (int i = lo + tid; i < hi; i += 512)
        atomicAdd(&h[rows[i] >> 12], 1);
    __syncthreads();
    if (tid < NSB && h[tid])
        h[tid] = atomicAdd(&gcurA[tid], h[tid]);    // base offset within super region
    __syncthreads();
    for (int i = lo + tid; i < hi; i += 512) {
        int r = rows[i];                             // L2-hot
        int s = r >> 12;
        int slot = atomicAdd(&h[s], 1);
        uint2 p;
        p.x = ((unsigned)(r & 4095) << 19) | (unsigned)cols[i];
        p.y = __float_as_uint(vals[i]);
        eg1[(size_t)s * cap_s + slot] = p;
    }
}

// ===== pass B1: per-(super,slice) 64-bin histogram =====
__global__ __launch_bounds__(512) void binBh_kernel(const int* __restrict__ lenA,
                                                    const uint2* __restrict__ eg1,
                                                    int* __restrict__ H, int cap_s) {
    __shared__ int h[64];
    const int sb = blockIdx.x / SLICES;
    const int sl = blockIdx.x % SLICES;
    const int len = lenA[sb];
    const int chunk = (len + SLICES - 1) / SLICES;
    const int lo = sl * chunk;
    const int hi = min(lo + chunk, len);
    const size_t base = (size_t)sb * cap_s;
    if (threadIdx.x < 64) h[threadIdx.x] = 0;
    __syncthreads();
    for (int i = lo + threadIdx.x; i < hi; i += 512)
        atomicAdd(&h[(eg1[base + i].x >> 25) & 63], 1);
    __syncthreads();
    if (threadIdx.x < 64)
        H[((size_t)sb * SLICES + sl) * 64 + threadIdx.x] = h[threadIdx.x];
}

// ===== scan: super lens -> superstart; H -> per-slice write bases + bstart =====
__global__ __launch_bounds__(128) void scan_all(const int* __restrict__ lenA,
                                                int* __restrict__ H,
                                                int* __restrict__ bstart, int nnz) {
    __shared__ int ss[NSB + 1];
    const int t = threadIdx.x;
    if (t == 0) {
        int acc = 0;
        for (int s = 0; s < NSB; ++s) { ss[s] = acc; acc += lenA[s]; }
        ss[NSB] = acc;
    }
    __syncthreads();
    for (int sb = t; sb < NSB; sb += 128) {
        int base = ss[sb];
        int nbk = min(64, NB - sb * 64);
        for (int b = 0; b < nbk; ++b) {
            bstart[sb * 64 + b] = base;
            int cur = base;
            for (int sl = 0; sl < SLICES; ++sl) {
                size_t idx = ((size_t)sb * SLICES + sl) * 64 + b;
                int c = H[idx];
                H[idx] = cur;
                cur += c;
            }
            base = cur;
        }
    }
    if (t == 0) bstart[NB] = nnz;
}

// ===== pass B2: scatter each slice into bucket-contiguous eg2 =====
__global__ __launch_bounds__(512) void binBs_kernel(const int* __restrict__ lenA,
                                                    const uint2* __restrict__ eg1,
                                                    const int* __restrict__ H,
                                                    uint2* __restrict__ eg2, int cap_s) {
    __shared__ int cur[64];
    const int sb = blockIdx.x / SLICES;
    const int sl = blockIdx.x % SLICES;
    const int len = lenA[sb];
    const int chunk = (len + SLICES - 1) / SLICES;
    const int lo = sl * chunk;
    const int hi = min(lo + chunk, len);
    const size_t base = (size_t)sb * cap_s;
    if (threadIdx.x < 64)
        cur[threadIdx.x] = H[((size_t)sb * SLICES + sl) * 64 + threadIdx.x];
    __syncthreads();
    for (int i = lo + threadIdx.x; i < hi; i += 512) {
        uint2 p = eg1[base + i];
        int slot = atomicAdd(&cur[(p.x >> 25) & 63], 1);
        eg2[slot] = p;
    }
}

// ======= fused: in-LDS row sort + base + neighbor + gather, one block per bucket =======
__global__ __launch_bounds__(256) void sortgather_kernel(
    const ushort* __restrict__ emb16,
    const int*   __restrict__ unb,   const float* __restrict__ uw,
    const int*   __restrict__ inb,   const float* __restrict__ iw,
    const int*   __restrict__ bstart, const uint2* __restrict__ eg,
    float* __restrict__ out)
{
    __shared__ uint2 lds_e[CAP];          // 18 KB
    __shared__ int h[RPB], st[RPB], cur[RPB];

    const int tid  = threadIdx.x;
    const int g    = tid >> 4;            // 16 groups
    const int sub  = tid & 15;
    const int d0   = sub * 4;
    const int k    = blockIdx.x;
    const int row0 = k * RPB;

    float4 acc[4];
    #pragma unroll
    for (int rr = 0; rr < 4; ++rr) {
        const int row = row0 + rr * 16 + g;
        if (row >= N_TOT) { acc[rr] = make_float4(0.f, 0.f, 0.f, 0.f); continue; }
        ushort4 ub = *reinterpret_cast<const ushort4*>(emb16 + (size_t)row * D + d0);
        float4 a = make_float4(bf2f(ub.x), bf2f(ub.y), bf2f(ub.z), bf2f(ub.w));
        if (row < N_USER) {
            const int*   nb = unb + (size_t)row * 10;
            const float* w  = uw  + (size_t)row * 10;
            #pragma unroll
            for (int q = 0; q < 10; ++q) {
                ushort4 u = *reinterpret_cast<const ushort4*>(emb16 + (size_t)nb[q] * D + d0);
                float wq = w[q];
                a.x += wq * bf2f(u.x); a.y += wq * bf2f(u.y);
                a.z += wq * bf2f(u.z); a.w += wq * bf2f(u.w);
            }
        } else {
            const int r = row - N_USER;
            const int*   nb = inb + (size_t)r * 10;
            const float* w  = iw  + (size_t)r * 10;
            #pragma unroll
            for (int q = 0; q < 10; ++q) {
                ushort4 u = *reinterpret_cast<const ushort4*>(emb16 + ((size_t)nb[q] + N_USER) * D + d0);
                float wq = w[q];
                a.x += wq * bf2f(u.x); a.y += wq * bf2f(u.y);
                a.z += wq * bf2f(u.z); a.w += wq * bf2f(u.w);
            }
        }
        acc[rr] = a;
    }

    const int s = bstart[k];
    const int e = bstart[k + 1];

    for (int cs = s; cs < e; cs += CAP) {
        const int n = min(e - cs, CAP);

        if (tid < RPB) h[tid] = 0;
        __syncthreads();
        for (int i = tid; i < n; i += 256)
            atomicAdd(&h[(eg[cs + i].x >> 19) & 63], 1);
        __syncthreads();
        if (tid < RPB) {                  // wave 0: 64-wide shfl scan
            int orig = h[tid];
            int v = orig;
            #pragma unroll
            for (int off = 1; off < RPB; off <<= 1) {
                int u = __shfl_up(v, off);
                if (tid >= off) v += u;
            }
            st[tid]  = v - orig;
            cur[tid] = v - orig;
        }
        __syncthreads();
        for (int i = tid; i < n; i += 256) {
            uint2 p = eg[cs + i];         // L2 hit
            int slot = atomicAdd(&cur[(p.x >> 19) & 63], 1);
            lds_e[slot] = p;
        }
        __syncthreads();

        #pragma unroll
        for (int rr = 0; rr < 4; ++rr) {
            const int r  = rr * 16 + g;
            const int b0 = st[r];
            const int cr = h[r];
            int j = 0;
            for (; j + 3 < cr; j += 4) {
                uint2 p0 = lds_e[b0 + j],     p1 = lds_e[b0 + j + 1];
                uint2 p2 = lds_e[b0 + j + 2], p3 = lds_e[b0 + j + 3];
                ushort4 u0 = *reinterpret_cast<const ushort4*>(emb16 + (size_t)(p0.x & 0x7FFFFu) * D + d0);
                ushort4 u1 = *reinterpret_cast<const ushort4*>(emb16 + (size_t)(p1.x & 0x7FFFFu) * D + d0);
                ushort4 u2 = *reinterpret_cast<const ushort4*>(emb16 + (size_t)(p2.x & 0x7FFFFu) * D + d0);
                ushort4 u3 = *reinterpret_cast<const ushort4*>(emb16 + (size_t)(p3.x & 0x7FFFFu) * D + d0);
                float a0 = __uint_as_float(p0.y), a1 = __uint_as_float(p1.y);
                float a2 = __uint_as_float(p2.y), a3 = __uint_as_float(p3.y);
                acc[rr].x += a0 * bf2f(u0.x); acc[rr].y += a0 * bf2f(u0.y);
                acc[rr].z += a0 * bf2f(u0.z); acc[rr].w += a0 * bf2f(u0.w);
                acc[rr].x += a1 * bf2f(u1.x); acc[rr].y += a1 * bf2f(u1.y);
                acc[rr].z += a1 * bf2f(u1.z); acc[rr].w += a1 * bf2f(u1.w);
                acc[rr].x += a2 * bf2f(u2.x); acc[rr].y += a2 * bf2f(u2.y);
                acc[rr].z += a2 * bf2f(u2.z); acc[rr].w += a2 * bf2f(u2.w);
                acc[rr].x += a3 * bf2f(u3.x); acc[rr].y += a3 * bf2f(u3.y);
                acc[rr].z += a3 * bf2f(u3.z); acc[rr].w += a3 * bf2f(u3.w);
            }
            for (; j < cr; ++j) {
                uint2 p = lds_e[b0 + j];
                ushort4 u = *reinterpret_cast<const ushort4*>(emb16 + (size_t)(p.x & 0x7FFFFu) * D + d0);
                float a = __uint_as_float(p.y);
                acc[rr].x += a * bf2f(u.x); acc[rr].y += a * bf2f(u.y);
                acc[rr].z += a * bf2f(u.z); acc[rr].w += a * bf2f(u.w);
            }
        }
        __syncthreads();
    }

    #pragma unroll
    for (int rr = 0; rr < 4; ++rr) {
        const int row = row0 + rr * 16 + g;
        if (row < N_TOT)
            *reinterpret_cast<float4*>(&out[(size_t)row * D + d0]) = acc[rr];
    }
}

// ================= tier-2: CSR build via global atomics + fp32 gather =================

__global__ void count_kernel(const int* __restrict__ rows, int* __restrict__ cnt, int nnz) {
    int i = blockIdx.x * blockDim.x + threadIdx.x;
    int stride = gridDim.x * blockDim.x;
    for (; i < nnz; i += stride) atomicAdd(&cnt[rows[i]], 1);
}

__global__ void scan_block_sums(const int* __restrict__ cnt, int* __restrict__ bsum, int n) {
    __shared__ int sdata[256];
    int base = blockIdx.x * SCAN_CHUNK;
    int s = 0;
    for (int t = threadIdx.x; t < SCAN_CHUNK; t += 256) {
        int idx = base + t;
        s += (idx < n) ? cnt[idx] : 0;
    }
    sdata[threadIdx.x] = s;
    __syncthreads();
    for (int off = 128; off > 0; off >>= 1) {
        if (threadIdx.x < off) sdata[threadIdx.x] += sdata[threadIdx.x + off];
        __syncthreads();
    }
    if (threadIdx.x == 0) bsum[blockIdx.x] = sdata[0];
}

__global__ void scan_bsum_kernel(int* __restrict__ bsum, int nb) {
    if (threadIdx.x == 0 && blockIdx.x == 0) {
        int acc = 0;
        for (int i = 0; i < nb; ++i) { int v = bsum[i]; bsum[i] = acc; acc += v; }
    }
}

__global__ void scan_final(const int* __restrict__ cnt, const int* __restrict__ bsum,
                           int* __restrict__ row_start, int n, int nnz) {
    __shared__ int sums[256];
    int b = blockIdx.x, t = threadIdx.x;
    int base = b * SCAN_CHUNK;
    int loc[8];
    int s = 0;
    #pragma unroll
    for (int k = 0; k < 8; ++k) {
        int idx = base + t * 8 + k;
        int v = (idx < n) ? cnt[idx] : 0;
        loc[k] = s; s += v;
    }
    sums[t] = s;
    __syncthreads();
    for (int off = 1; off < 256; off <<= 1) {
        int v = (t >= off) ? sums[t - off] : 0;
        __syncthreads();
        sums[t] += v;
        __syncthreads();
    }
    int off0 = bsum[b] + (sums[t] - s);
    #pragma unroll
    for (int k = 0; k < 8; ++k) {
        int idx = base + t * 8 + k;
        if (idx < n) row_start[idx] = off0 + loc[k];
    }
    if (b == gridDim.x - 1 && t == 255) row_start[n] = nnz;
}

__global__ void fill_kernel(const int* __restrict__ rows, const int* __restrict__ cols,
                            const float* __restrict__ vals, const int* __restrict__ row_start,
                            int* __restrict__ pos, uint2* __restrict__ eg, int nnz) {
    int i = blockIdx.x * blockDim.x + threadIdx.x;
    int stride = gridDim.x * blockDim.x;
    for (; i < nnz; i += stride) {
        int r = rows[i];
        int p = atomicAdd(&pos[r], 1);
        uint2 e;
        e.x = (unsigned)cols[i];
        e.y = __float_as_uint(vals[i]);
        eg[row_start[r] + p] = e;
    }
}

__global__ __launch_bounds__(256) void gather16_kernel(
    const float* __restrict__ users, const float* __restrict__ items,
    const int*   __restrict__ unb,   const float* __restrict__ uw,
    const int*   __restrict__ inb,   const float* __restrict__ iw,
    const int*   __restrict__ row_start, const uint2* __restrict__ eg,
    float* __restrict__ out)
{
    const int tid = threadIdx.x;
    const int grp = tid >> 4;
    const int sub = tid & 15;
    const int row = blockIdx.x * 16 + grp;
    if (row >= N_TOT) return;
    const int d0 = sub * 4;

    float4 acc;
    if (row < N_USER) {
        acc = *reinterpret_cast<const float4*>(&users[(size_t)row * D + d0]);
        const int*   nb = unb + (size_t)row * 10;
        const float* w  = uw  + (size_t)row * 10;
        #pragma unroll
        for (int q = 0; q < 10; ++q) {
            float4 v = *reinterpret_cast<const float4*>(&users[(size_t)nb[q] * D + d0]);
            float wq = w[q];
            acc.x += wq * v.x; acc.y += wq * v.y; acc.z += wq * v.z; acc.w += wq * v.w;
        }
    } else {
        int r = row - N_USER;
        acc = *reinterpret_cast<const float4*>(&items[(size_t)r * D + d0]);
        const int*   nb = inb + (size_t)r * 10;
        const float* w  = iw  + (size_t)r * 10;
        #pragma unroll
        for (int q = 0; q < 10; ++q) {
            float4 v = *reinterpret_cast<const float4*>(&items[(size_t)nb[q] * D + d0]);
            float wq = w[q];
            acc.x += wq * v.x; acc.y += wq * v.y; acc.z += wq * v.z; acc.w += wq * v.w;
        }
    }

    const int s = row_start[row];
    const int e = row_start[row + 1];
    for (int i = s; i < e; ++i) {
        uint2 p = eg[i];
        int c = (int)(p.x & 0x7FFFFu);
        const float* src = (c < N_USER) ? users + (size_t)c * D : items + (size_t)(c - N_USER) * D;
        float4 v = *reinterpret_cast<const float4*>(src + d0);
        float a = __uint_as_float(p.y);
        acc.x += a * v.x; acc.y += a * v.y; acc.z += a * v.z; acc.w += a * v.w;
    }

    *reinterpret_cast<float4*>(&out[(size_t)row * D + d0]) = acc;
}

// ================= tier-3 fallback: scatter =================
__global__ __launch_bounds__(256) void base_neighbor_kernel(
    const float* __restrict__ users, const float* __restrict__ items,
    const int*   __restrict__ unb,   const float* __restrict__ uw,
    const int*   __restrict__ inb,   const float* __restrict__ iw,
    float* __restrict__ out)
{
    int gtid = blockIdx.x * blockDim.x + threadIdx.x;
    int row  = gtid >> 6;
    int lane = gtid & 63;
    if (row >= N_TOT) return;
    float acc;
    if (row < N_USER) {
        acc = users[(size_t)row * D + lane];
        const int*   nb = unb + (size_t)row * 10;
        const float* w  = uw  + (size_t)row * 10;
        #pragma unroll
        for (int q = 0; q < 10; ++q) acc += w[q] * users[(size_t)nb[q] * D + lane];
    } else {
        int r = row - N_USER;
        acc = items[(size_t)r * D + lane];
        const int*   nb = inb + (size_t)r * 10;
        const float* w  = iw  + (size_t)r * 10;
        #pragma unroll
        for (int q = 0; q < 10; ++q) acc += w[q] * items[(size_t)nb[q] * D + lane];
    }
    out[(size_t)row * D + lane] = acc;
}

__global__ __launch_bounds__(256) void edge_scatter_kernel(
    const float* __restrict__ users, const float* __restrict__ items,
    const int*   __restrict__ rows,  const int* __restrict__ cols,
    const float* __restrict__ vals,
    float* __restrict__ out, int nnz)
{
    int gtid = blockIdx.x * blockDim.x + threadIdx.x;
    int e    = gtid >> 6;
    int lane = gtid & 63;
    if (e >= nnz) return;
    int   r = rows[e];
    int   c = cols[e];
    float v = vals[e];
    const float* src = (c < N_USER) ? (users + (size_t)c * D)
                                    : (items + (size_t)(c - N_USER) * D);
    atomicAdd(&out[(size_t)r * D + lane], v * src[lane]);
}

extern "C" void kernel_launch(void* const* d_in, const int* in_sizes, int n_in,
                              void* d_out, int out_size, void* d_ws, size_t ws_size,
                              hipStream_t stream) {
    const float* users = (const float*)d_in[0];
    const float* items = (const float*)d_in[1];
    const int*   unb   = (const int*)  d_in[2];
    const float* uw    = (const float*)d_in[3];
    const int*   inb   = (const int*)  d_in[4];
    const float* iw    = (const float*)d_in[5];
    const int*   grow  = (const int*)  d_in[6];
    const int*   gcol  = (const int*)  d_in[7];
    const float* gval  = (const float*)d_in[8];
    float* out = (float*)d_out;

    const int nnz = in_sizes[6];
    const int cap_s = nnz / NSB + 16384;   // ~45 sigma slack over Poisson spread

    const size_t A = 255;
    const size_t sz_eg1    = (((size_t)NSB * cap_s * 8) + A) & ~A;
    const size_t sz_eg2    = (((size_t)nnz * 8) + A) & ~A;
    const size_t sz_H      = (((size_t)NSB * SLICES * 64 * 4) + A) & ~A;
    const size_t sz_bstart = (((size_t)(NB + 1) * 4) + A) & ~A;
    const size_t sz_gcurA  = (((size_t)NSB * 4) + A) & ~A;
    const size_t sz_emb16  = (((size_t)N_TOT * D * 2) + A) & ~A;
    const size_t need0 = sz_eg1 + sz_eg2 + sz_H + sz_bstart + sz_gcurA + sz_emb16;

    const size_t sz_eg       = (((size_t)nnz * 8) + A) & ~A;
    const size_t sz_rowstart = (((size_t)(N_TOT + 1) * 4) + A) & ~A;
    const size_t sz_cnt  = (((size_t)N_TOT * 4) + A) & ~A;
    const int    nb2     = (N_TOT + SCAN_CHUNK - 1) / SCAN_CHUNK;
    const size_t sz_bsum = (((size_t)nb2 * 4) + A) & ~A;
    const size_t need2 = sz_eg + sz_rowstart + sz_cnt + sz_bsum;

    if (ws_size >= need0) {
        char* wsp = (char*)d_ws;
        uint2*  eg1    = (uint2*)wsp;  wsp += sz_eg1;
        uint2*  eg2    = (uint2*)wsp;  wsp += sz_eg2;
        int*    H      = (int*)wsp;    wsp += sz_H;
        int*    bstart = (int*)wsp;    wsp += sz_bstart;
        int*    gcurA  = (int*)wsp;    wsp += sz_gcurA;
        ushort* emb16  = (ushort*)wsp;

        const int chunkA = (nnz + NBLK_A - 1) / NBLK_A;
        const int conv_grid = (int)(((size_t)N_TOT * D / 4 + 255) / 256);

        conv_kernel<<<conv_grid, 256, 0, stream>>>(users, items, emb16);
        hipMemsetAsync(gcurA, 0, (size_t)NSB * 4, stream);
        binA_kernel<<<NBLK_A, 512, 0, stream>>>(grow, gcol, gval, gcurA,
                                                eg1, nnz, chunkA, cap_s);
        binBh_kernel<<<NSB * SLICES, 512, 0, stream>>>(gcurA, eg1, H, cap_s);
        scan_all<<<1, 128, 0, stream>>>(gcurA, H, bstart, nnz);
        binBs_kernel<<<NSB * SLICES, 512, 0, stream>>>(gcurA, eg1, H, eg2, cap_s);
        sortgather_kernel<<<NB, 256, 0, stream>>>(emb16, unb, uw, inb, iw,
                                                  bstart, eg2, out);
    } else if (ws_size >= need2) {
        char* wsp = (char*)d_ws;
        uint2* eg        = (uint2*)wsp;  wsp += sz_eg;
        int*   row_start = (int*)wsp;    wsp += sz_rowstart;
        int*   cnt       = (int*)wsp;    wsp += sz_cnt;
        int*   bsum      = (int*)wsp;

        hipMemsetAsync(cnt, 0, (size_t)N_TOT * 4, stream);
        count_kernel<<<2048, 256, 0, stream>>>(grow, cnt, nnz);
        scan_block_sums<<<nb2, 256, 0, stream>>>(cnt, bsum, N_TOT);
        scan_bsum_kernel<<<1, 64, 0, stream>>>(bsum, nb2);
        scan_final<<<nb2, 256, 0, stream>>>(cnt, bsum, row_start, N_TOT, nnz);
        hipMemsetAsync(cnt, 0, (size_t)N_TOT * 4, stream);
        fill_kernel<<<2048, 256, 0, stream>>>(grow, gcol, gval, row_start, cnt, eg, nnz);
        const int g16_grid = (N_TOT + 15) / 16;
        gather16_kernel<<<g16_grid, 256, 0, stream>>>(users, items, unb, uw, inb, iw,
                                                      row_start, eg, out);
    } else {
        int grid = (int)(((long long)N_TOT * 64 + 255) / 256);
        base_neighbor_kernel<<<grid, 256, 0, stream>>>(users, items, unb, uw, inb, iw, out);
        long long ethreads = (long long)nnz * 64;
        long long egrid = (ethreads + 255) / 256;
        edge_scatter_kernel<<<(int)egrid, 256, 0, stream>>>(users, items, grow, gcol, gval, out, nnz);
    }
}

// Round 15
// 465.225 us; speedup vs baseline: 1.2261x; 1.0921x over previous
//
#include <hip/hip_runtime.h>

#define N_USER 100000
#define N_ITEM 200000
#define N_TOT  (N_USER + N_ITEM)
#define D      64
#define RPB    64                        // rows per bucket
#define NB     ((N_TOT + RPB - 1) / RPB) // 4688 buckets
#define NSB    ((NB + 63) / 64)          // 74 super-buckets (4096 rows each)
#define NBH    (NSB * 64)                // padded hist size (4736)
#define SLICES 8                         // binB blocks per super
#define NBLK_A 512                       // binA blocks
#define CAP    2304                      // sortgather LDS edge capacity per chunk
#define SCAN_CHUNK 2048                  // tier-2 scan

__device__ __forceinline__ unsigned short f2bf(float f) {
    unsigned b = __float_as_uint(f);
    unsigned r = (b + 0x7FFFu + ((b >> 16) & 1u)) >> 16;   // RNE
    return (unsigned short)r;
}
__device__ __forceinline__ float bf2f(unsigned short u) {
    return __uint_as_float(((unsigned)u) << 16);
}

// ================= emb -> bf16 =================
__global__ __launch_bounds__(256) void conv_kernel(const float* __restrict__ users,
                                                   const float* __restrict__ items,
                                                   ushort* __restrict__ emb16) {
    size_t i = (size_t)blockIdx.x * blockDim.x + threadIdx.x;
    const size_t total = (size_t)N_TOT * D / 4;
    if (i >= total) return;
    size_t e0 = i * 4;
    const size_t usz = (size_t)N_USER * D;
    const float* src = (e0 < usz) ? users + e0 : items + (e0 - usz);
    float4 v = *reinterpret_cast<const float4*>(src);
    ushort4 o;
    o.x = f2bf(v.x); o.y = f2bf(v.y); o.z = f2bf(v.z); o.w = f2bf(v.w);
    *reinterpret_cast<ushort4*>(emb16 + e0) = o;
}

// ===== pass A (fused count): NB-bin LDS hist -> totB atomics + super reserve + scatter =====
__global__ __launch_bounds__(512) void binA_kernel(const int* __restrict__ rows,
                                                   const int* __restrict__ cols,
                                                   const float* __restrict__ vals,
                                                   int* __restrict__ totB,
                                                   int* __restrict__ gcurA,
                                                   uint2* __restrict__ eg1,
                                                   int nnz, int chunk, int cap_s) {
    __shared__ int h[NBH];                // 18.5 KB, padded to NSB*64
    __shared__ int sp[NSB * 4];           // partial super sums
    __shared__ int sbase[NSB];            // super scatter cursors
    const int tid = threadIdx.x;

    for (int k = tid; k < NBH; k += 512) h[k] = 0;
    __syncthreads();

    const int lo = blockIdx.x * chunk;
    const int hi = min(lo + chunk, nnz);
    for (int i = lo + tid; i < hi; i += 512)
        atomicAdd(&h[rows[i] >> 6], 1);
    __syncthreads();

    // per-bucket totals -> global (count2 fused)
    for (int k = tid; k < NB; k += 512)
        if (h[k]) atomicAdd(&totB[k], h[k]);

    // super partial sums: 4 threads per super, 16 bins each
    if (tid < NSB * 4) {
        const int s = tid >> 2, part = tid & 3;
        int acc = 0;
        #pragma unroll
        for (int j = 0; j < 16; ++j) acc += h[s * 64 + part * 16 + j];
        sp[tid] = acc;
    }
    __syncthreads();
    if (tid < NSB) {
        int tot = sp[tid * 4] + sp[tid * 4 + 1] + sp[tid * 4 + 2] + sp[tid * 4 + 3];
        sbase[tid] = tot ? atomicAdd(&gcurA[tid], tot) : 0;
    }
    __syncthreads();

    for (int i = lo + tid; i < hi; i += 512) {
        int r = rows[i];                             // L2-hot
        int s = r >> 12;
        int slot = atomicAdd(&sbase[s], 1);
        uint2 p;
        p.x = ((unsigned)(r & 4095) << 19) | (unsigned)cols[i];
        p.y = __float_as_uint(vals[i]);
        eg1[(size_t)s * cap_s + slot] = p;
    }
}

// ===== scan: bucket totals -> bstart + gcurB =====
__global__ __launch_bounds__(1024) void scan_kernel(const int* __restrict__ totB,
                                                    int* __restrict__ bstart,
                                                    int* __restrict__ gcurB, int nnz) {
    __shared__ int s[1024];
    const int t = threadIdx.x;
    const int PER = (NB + 1023) / 1024;   // 5
    int loc[8];
    int sum = 0;
    #pragma unroll
    for (int k = 0; k < PER; ++k) {
        int idx = t * PER + k;
        int v = (idx < NB) ? totB[idx] : 0;
        loc[k] = sum; sum += v;
    }
    s[t] = sum;
    __syncthreads();
    for (int off = 1; off < 1024; off <<= 1) {
        int v = (t >= off) ? s[t - off] : 0;
        __syncthreads();
        s[t] += v;
        __syncthreads();
    }
    int base = s[t] - sum;
    #pragma unroll
    for (int k = 0; k < PER; ++k) {
        int idx = t * PER + k;
        if (idx < NB) { bstart[idx] = base + loc[k]; gcurB[idx] = base + loc[k]; }
    }
    if (t == 1023) bstart[NB] = nnz;
}

// ===== pass B (single kernel): per-(super,slice) hist -> reserve -> L2-hot scatter =====
__global__ __launch_bounds__(512) void binB_kernel(const int* __restrict__ lenA,
                                                   int* __restrict__ gcurB,
                                                   const uint2* __restrict__ eg1,
                                                   uint2* __restrict__ eg2, int cap_s) {
    __shared__ int h[64];
    const int sb = blockIdx.x / SLICES;
    const int sl = blockIdx.x % SLICES;
    const int len = lenA[sb];
    const int chunk = (len + SLICES - 1) / SLICES;
    const int lo = sl * chunk;
    const int hi = min(lo + chunk, len);
    const size_t base = (size_t)sb * cap_s;

    if (threadIdx.x < 64) h[threadIdx.x] = 0;
    __syncthreads();
    for (int i = lo + threadIdx.x; i < hi; i += 512)
        atomicAdd(&h[(eg1[base + i].x >> 25) & 63], 1);
    __syncthreads();
    if (threadIdx.x < 64) {
        int b = sb * 64 + threadIdx.x;
        if (b < NB && h[threadIdx.x])
            h[threadIdx.x] = atomicAdd(&gcurB[b], h[threadIdx.x]);
    }
    __syncthreads();
    for (int i = lo + threadIdx.x; i < hi; i += 512) {
        uint2 p = eg1[base + i];          // L2-hot (hist pass above)
        int slot = atomicAdd(&h[(p.x >> 25) & 63], 1);
        eg2[slot] = p;
    }
}

// ======= fused: in-LDS row sort + base + neighbor + gather, one block per bucket =======
__global__ __launch_bounds__(256) void sortgather_kernel(
    const ushort* __restrict__ emb16,
    const int*   __restrict__ unb,   const float* __restrict__ uw,
    const int*   __restrict__ inb,   const float* __restrict__ iw,
    const int*   __restrict__ bstart, const uint2* __restrict__ eg,
    float* __restrict__ out)
{
    __shared__ uint2 lds_e[CAP];          // 18 KB
    __shared__ int h[RPB], st[RPB], cur[RPB];

    const int tid  = threadIdx.x;
    const int g    = tid >> 4;            // 16 groups
    const int sub  = tid & 15;
    const int d0   = sub * 4;
    const int k    = blockIdx.x;
    const int row0 = k * RPB;

    float4 acc[4];
    #pragma unroll
    for (int rr = 0; rr < 4; ++rr) {
        const int row = row0 + rr * 16 + g;
        if (row >= N_TOT) { acc[rr] = make_float4(0.f, 0.f, 0.f, 0.f); continue; }
        ushort4 ub = *reinterpret_cast<const ushort4*>(emb16 + (size_t)row * D + d0);
        float4 a = make_float4(bf2f(ub.x), bf2f(ub.y), bf2f(ub.z), bf2f(ub.w));
        if (row < N_USER) {
            const int*   nb = unb + (size_t)row * 10;
            const float* w  = uw  + (size_t)row * 10;
            #pragma unroll
            for (int q = 0; q < 10; ++q) {
                ushort4 u = *reinterpret_cast<const ushort4*>(emb16 + (size_t)nb[q] * D + d0);
                float wq = w[q];
                a.x += wq * bf2f(u.x); a.y += wq * bf2f(u.y);
                a.z += wq * bf2f(u.z); a.w += wq * bf2f(u.w);
            }
        } else {
            const int r = row - N_USER;
            const int*   nb = inb + (size_t)r * 10;
            const float* w  = iw  + (size_t)r * 10;
            #pragma unroll
            for (int q = 0; q < 10; ++q) {
                ushort4 u = *reinterpret_cast<const ushort4*>(emb16 + ((size_t)nb[q] + N_USER) * D + d0);
                float wq = w[q];
                a.x += wq * bf2f(u.x); a.y += wq * bf2f(u.y);
                a.z += wq * bf2f(u.z); a.w += wq * bf2f(u.w);
            }
        }
        acc[rr] = a;
    }

    const int s = bstart[k];
    const int e = bstart[k + 1];

    for (int cs = s; cs < e; cs += CAP) {
        const int n = min(e - cs, CAP);

        if (tid < RPB) h[tid] = 0;
        __syncthreads();
        for (int i = tid; i < n; i += 256)
            atomicAdd(&h[(eg[cs + i].x >> 19) & 63], 1);
        __syncthreads();
        if (tid < RPB) {                  // wave 0: 64-wide shfl scan
            int orig = h[tid];
            int v = orig;
            #pragma unroll
            for (int off = 1; off < RPB; off <<= 1) {
                int u = __shfl_up(v, off);
                if (tid >= off) v += u;
            }
            st[tid]  = v - orig;
            cur[tid] = v - orig;
        }
        __syncthreads();
        for (int i = tid; i < n; i += 256) {
            uint2 p = eg[cs + i];         // L2 hit
            int slot = atomicAdd(&cur[(p.x >> 19) & 63], 1);
            lds_e[slot] = p;
        }
        __syncthreads();

        #pragma unroll
        for (int rr = 0; rr < 4; ++rr) {
            const int r  = rr * 16 + g;
            const int b0 = st[r];
            const int cr = h[r];
            int j = 0;
            for (; j + 3 < cr; j += 4) {
                uint2 p0 = lds_e[b0 + j],     p1 = lds_e[b0 + j + 1];
                uint2 p2 = lds_e[b0 + j + 2], p3 = lds_e[b0 + j + 3];
                ushort4 u0 = *reinterpret_cast<const ushort4*>(emb16 + (size_t)(p0.x & 0x7FFFFu) * D + d0);
                ushort4 u1 = *reinterpret_cast<const ushort4*>(emb16 + (size_t)(p1.x & 0x7FFFFu) * D + d0);
                ushort4 u2 = *reinterpret_cast<const ushort4*>(emb16 + (size_t)(p2.x & 0x7FFFFu) * D + d0);
                ushort4 u3 = *reinterpret_cast<const ushort4*>(emb16 + (size_t)(p3.x & 0x7FFFFu) * D + d0);
                float a0 = __uint_as_float(p0.y), a1 = __uint_as_float(p1.y);
                float a2 = __uint_as_float(p2.y), a3 = __uint_as_float(p3.y);
                acc[rr].x += a0 * bf2f(u0.x); acc[rr].y += a0 * bf2f(u0.y);
                acc[rr].z += a0 * bf2f(u0.z); acc[rr].w += a0 * bf2f(u0.w);
                acc[rr].x += a1 * bf2f(u1.x); acc[rr].y += a1 * bf2f(u1.y);
                acc[rr].z += a1 * bf2f(u1.z); acc[rr].w += a1 * bf2f(u1.w);
                acc[rr].x += a2 * bf2f(u2.x); acc[rr].y += a2 * bf2f(u2.y);
                acc[rr].z += a2 * bf2f(u2.z); acc[rr].w += a2 * bf2f(u2.w);
                acc[rr].x += a3 * bf2f(u3.x); acc[rr].y += a3 * bf2f(u3.y);
                acc[rr].z += a3 * bf2f(u3.z); acc[rr].w += a3 * bf2f(u3.w);
            }
            for (; j < cr; ++j) {
                uint2 p = lds_e[b0 + j];
                ushort4 u = *reinterpret_cast<const ushort4*>(emb16 + (size_t)(p.x & 0x7FFFFu) * D + d0);
                float a = __uint_as_float(p.y);
                acc[rr].x += a * bf2f(u.x); acc[rr].y += a * bf2f(u.y);
                acc[rr].z += a * bf2f(u.z); acc[rr].w += a * bf2f(u.w);
            }
        }
        __syncthreads();
    }

    #pragma unroll
    for (int rr = 0; rr < 4; ++rr) {
        const int row = row0 + rr * 16 + g;
        if (row < N_TOT)
            *reinterpret_cast<float4*>(&out[(size_t)row * D + d0]) = acc[rr];
    }
}

// ================= tier-2: CSR build via global atomics + fp32 gather =================

__global__ void count_kernel(const int* __restrict__ rows, int* __restrict__ cnt, int nnz) {
    int i = blockIdx.x * blockDim.x + threadIdx.x;
    int stride = gridDim.x * blockDim.x;
    for (; i < nnz; i += stride) atomicAdd(&cnt[rows[i]], 1);
}

__global__ void scan_block_sums(const int* __restrict__ cnt, int* __restrict__ bsum, int n) {
    __shared__ int sdata[256];
    int base = blockIdx.x * SCAN_CHUNK;
    int s = 0;
    for (int t = threadIdx.x; t < SCAN_CHUNK; t += 256) {
        int idx = base + t;
        s += (idx < n) ? cnt[idx] : 0;
    }
    sdata[threadIdx.x] = s;
    __syncthreads();
    for (int off = 128; off > 0; off >>= 1) {
        if (threadIdx.x < off) sdata[threadIdx.x] += sdata[threadIdx.x + off];
        __syncthreads();
    }
    if (threadIdx.x == 0) bsum[blockIdx.x] = sdata[0];
}

__global__ void scan_bsum_kernel(int* __restrict__ bsum, int nb) {
    if (threadIdx.x == 0 && blockIdx.x == 0) {
        int acc = 0;
        for (int i = 0; i < nb; ++i) { int v = bsum[i]; bsum[i] = acc; acc += v; }
    }
}

__global__ void scan_final(const int* __restrict__ cnt, const int* __restrict__ bsum,
                           int* __restrict__ row_start, int n, int nnz) {
    __shared__ int sums[256];
    int b = blockIdx.x, t = threadIdx.x;
    int base = b * SCAN_CHUNK;
    int loc[8];
    int s = 0;
    #pragma unroll
    for (int k = 0; k < 8; ++k) {
        int idx = base + t * 8 + k;
        int v = (idx < n) ? cnt[idx] : 0;
        loc[k] = s; s += v;
    }
    sums[t] = s;
    __syncthreads();
    for (int off = 1; off < 256; off <<= 1) {
        int v = (t >= off) ? sums[t - off] : 0;
        __syncthreads();
        sums[t] += v;
        __syncthreads();
    }
    int off0 = bsum[b] + (sums[t] - s);
    #pragma unroll
    for (int k = 0; k < 8; ++k) {
        int idx = base + t * 8 + k;
        if (idx < n) row_start[idx] = off0 + loc[k];
    }
    if (b == gridDim.x - 1 && t == 255) row_start[n] = nnz;
}

__global__ void fill_kernel(const int* __restrict__ rows, const int* __restrict__ cols,
                            const float* __restrict__ vals, const int* __restrict__ row_start,
                            int* __restrict__ pos, uint2* __restrict__ eg, int nnz) {
    int i = blockIdx.x * blockDim.x + threadIdx.x;
    int stride = gridDim.x * blockDim.x;
    for (; i < nnz; i += stride) {
        int r = rows[i];
        int p = atomicAdd(&pos[r], 1);
        uint2 e;
        e.x = (unsigned)cols[i];
        e.y = __float_as_uint(vals[i]);
        eg[row_start[r] + p] = e;
    }
}

__global__ __launch_bounds__(256) void gather16_kernel(
    const float* __restrict__ users, const float* __restrict__ items,
    const int*   __restrict__ unb,   const float* __restrict__ uw,
    const int*   __restrict__ inb,   const float* __restrict__ iw,
    const int*   __restrict__ row_start, const uint2* __restrict__ eg,
    float* __restrict__ out)
{
    const int tid = threadIdx.x;
    const int grp = tid >> 4;
    const int sub = tid & 15;
    const int row = blockIdx.x * 16 + grp;
    if (row >= N_TOT) return;
    const int d0 = sub * 4;

    float4 acc;
    if (row < N_USER) {
        acc = *reinterpret_cast<const float4*>(&users[(size_t)row * D + d0]);
        const int*   nb = unb + (size_t)row * 10;
        const float* w  = uw  + (size_t)row * 10;
        #pragma unroll
        for (int q = 0; q < 10; ++q) {
            float4 v = *reinterpret_cast<const float4*>(&users[(size_t)nb[q] * D + d0]);
            float wq = w[q];
            acc.x += wq * v.x; acc.y += wq * v.y; acc.z += wq * v.z; acc.w += wq * v.w;
        }
    } else {
        int r = row - N_USER;
        acc = *reinterpret_cast<const float4*>(&items[(size_t)r * D + d0]);
        const int*   nb = inb + (size_t)r * 10;
        const float* w  = iw  + (size_t)r * 10;
        #pragma unroll
        for (int q = 0; q < 10; ++q) {
            float4 v = *reinterpret_cast<const float4*>(&items[(size_t)nb[q] * D + d0]);
            float wq = w[q];
            acc.x += wq * v.x; acc.y += wq * v.y; acc.z += wq * v.z; acc.w += wq * v.w;
        }
    }

    const int s = row_start[row];
    const int e = row_start[row + 1];
    for (int i = s; i < e; ++i) {
        uint2 p = eg[i];
        int c = (int)(p.x & 0x7FFFFu);
        const float* src = (c < N_USER) ? users + (size_t)c * D : items + (size_t)(c - N_USER) * D;
        float4 v = *reinterpret_cast<const float4*>(src + d0);
        float a = __uint_as_float(p.y);
        acc.x += a * v.x; acc.y += a * v.y; acc.z += a * v.z; acc.w += a * v.w;
    }

    *reinterpret_cast<float4*>(&out[(size_t)row * D + d0]) = acc;
}

// ================= tier-3 fallback: scatter =================
__global__ __launch_bounds__(256) void base_neighbor_kernel(
    const float* __restrict__ users, const float* __restrict__ items,
    const int*   __restrict__ unb,   const float* __restrict__ uw,
    const int*   __restrict__ inb,   const float* __restrict__ iw,
    float* __restrict__ out)
{
    int gtid = blockIdx.x * blockDim.x + threadIdx.x;
    int row  = gtid >> 6;
    int lane = gtid & 63;
    if (row >= N_TOT) return;
    float acc;
    if (row < N_USER) {
        acc = users[(size_t)row * D + lane];
        const int*   nb = unb + (size_t)row * 10;
        const float* w  = uw  + (size_t)row * 10;
        #pragma unroll
        for (int q = 0; q < 10; ++q) acc += w[q] * users[(size_t)nb[q] * D + lane];
    } else {
        int r = row - N_USER;
        acc = items[(size_t)r * D + lane];
        const int*   nb = inb + (size_t)r * 10;
        const float* w  = iw  + (size_t)r * 10;
        #pragma unroll
        for (int q = 0; q < 10; ++q) acc += w[q] * items[(size_t)nb[q] * D + lane];
    }
    out[(size_t)row * D + lane] = acc;
}

__global__ __launch_bounds__(256) void edge_scatter_kernel(
    const float* __restrict__ users, const float* __restrict__ items,
    const int*   __restrict__ rows,  const int* __restrict__ cols,
    const float* __restrict__ vals,
    float* __restrict__ out, int nnz)
{
    int gtid = blockIdx.x * blockDim.x + threadIdx.x;
    int e    = gtid >> 6;
    int lane = gtid & 63;
    if (e >= nnz) return;
    int   r = rows[e];
    int   c = cols[e];
    float v = vals[e];
    const float* src = (c < N_USER) ? (users + (size_t)c * D)
                                    : (items + (size_t)(c - N_USER) * D);
    atomicAdd(&out[(size_t)r * D + lane], v * src[lane]);
}

extern "C" void kernel_launch(void* const* d_in, const int* in_sizes, int n_in,
                              void* d_out, int out_size, void* d_ws, size_t ws_size,
                              hipStream_t stream) {
    const float* users = (const float*)d_in[0];
    const float* items = (const float*)d_in[1];
    const int*   unb   = (const int*)  d_in[2];
    const float* uw    = (const float*)d_in[3];
    const int*   inb   = (const int*)  d_in[4];
    const float* iw    = (const float*)d_in[5];
    const int*   grow  = (const int*)  d_in[6];
    const int*   gcol  = (const int*)  d_in[7];
    const float* gval  = (const float*)d_in[8];
    float* out = (float*)d_out;

    const int nnz = in_sizes[6];
    const int cap_s = nnz / NSB + 16384;   // ~45 sigma slack over Poisson spread

    const size_t A = 255;
    const size_t sz_eg1    = (((size_t)NSB * cap_s * 8) + A) & ~A;
    const size_t sz_eg2    = (((size_t)nnz * 8) + A) & ~A;
    const size_t sz_totB   = (((size_t)NB * 4) + A) & ~A;
    const size_t sz_bstart = (((size_t)(NB + 1) * 4) + A) & ~A;
    const size_t sz_gcurB  = (((size_t)NB * 4) + A) & ~A;
    const size_t sz_gcurA  = (((size_t)NSB * 4) + A) & ~A;
    const size_t sz_emb16  = (((size_t)N_TOT * D * 2) + A) & ~A;
    const size_t need0 = sz_eg1 + sz_eg2 + sz_totB + sz_bstart + sz_gcurB + sz_gcurA + sz_emb16;

    const size_t sz_eg       = (((size_t)nnz * 8) + A) & ~A;
    const size_t sz_rowstart = (((size_t)(N_TOT + 1) * 4) + A) & ~A;
    const size_t sz_cnt  = (((size_t)N_TOT * 4) + A) & ~A;
    const int    nb2     = (N_TOT + SCAN_CHUNK - 1) / SCAN_CHUNK;
    const size_t sz_bsum = (((size_t)nb2 * 4) + A) & ~A;
    const size_t need2 = sz_eg + sz_rowstart + sz_cnt + sz_bsum;

    if (ws_size >= need0) {
        char* wsp = (char*)d_ws;
        uint2*  eg1    = (uint2*)wsp;  wsp += sz_eg1;
        uint2*  eg2    = (uint2*)wsp;  wsp += sz_eg2;
        int*    totB   = (int*)wsp;    wsp += sz_totB;
        int*    bstart = (int*)wsp;    wsp += sz_bstart;
        int*    gcurB  = (int*)wsp;    wsp += sz_gcurB;
        int*    gcurA  = (int*)wsp;    wsp += sz_gcurA;
        ushort* emb16  = (ushort*)wsp;

        const int chunkA = (nnz + NBLK_A - 1) / NBLK_A;
        const int conv_grid = (int)(((size_t)N_TOT * D / 4 + 255) / 256);

        conv_kernel<<<conv_grid, 256, 0, stream>>>(users, items, emb16);
        hipMemsetAsync(totB, 0, (size_t)NB * 4, stream);
        hipMemsetAsync(gcurA, 0, (size_t)NSB * 4, stream);
        binA_kernel<<<NBLK_A, 512, 0, stream>>>(grow, gcol, gval, totB, gcurA,
                                                eg1, nnz, chunkA, cap_s);
        scan_kernel<<<1, 1024, 0, stream>>>(totB, bstart, gcurB, nnz);
        binB_kernel<<<NSB * SLICES, 512, 0, stream>>>(gcurA, gcurB, eg1, eg2, cap_s);
        sortgather_kernel<<<NB, 256, 0, stream>>>(emb16, unb, uw, inb, iw,
                                                  bstart, eg2, out);
    } else if (ws_size >= need2) {
        char* wsp = (char*)d_ws;
        uint2* eg        = (uint2*)wsp;  wsp += sz_eg;
        int*   row_start = (int*)wsp;    wsp += sz_rowstart;
        int*   cnt       = (int*)wsp;    wsp += sz_cnt;
        int*   bsum      = (int*)wsp;

        hipMemsetAsync(cnt, 0, (size_t)N_TOT * 4, stream);
        count_kernel<<<2048, 256, 0, stream>>>(grow, cnt, nnz);
        scan_block_sums<<<nb2, 256, 0, stream>>>(cnt, bsum, N_TOT);
        scan_bsum_kernel<<<1, 64, 0, stream>>>(bsum, nb2);
        scan_final<<<nb2, 256, 0, stream>>>(cnt, bsum, row_start, N_TOT, nnz);
        hipMemsetAsync(cnt, 0, (size_t)N_TOT * 4, stream);
        fill_kernel<<<2048, 256, 0, stream>>>(grow, gcol, gval, row_start, cnt, eg, nnz);
        const int g16_grid = (N_TOT + 15) / 16;
        gather16_kernel<<<g16_grid, 256, 0, stream>>>(users, items, unb, uw, inb, iw,
                                                      row_start, eg, out);
    } else {
        int grid = (int)(((long long)N_TOT * 64 + 255) / 256);
        base_neighbor_kernel<<<grid, 256, 0, stream>>>(users, items, unb, uw, inb, iw, out);
        long long ethreads = (long long)nnz * 64;
        long long egrid = (ethreads + 255) / 256;
        edge_scatter_kernel<<<(int)egrid, 256, 0, stream>>>(users, items, grow, gcol, gval, out, nnz);
    }
}